// Round 7
// baseline (413.857 us; speedup 1.0000x reference)
//
#include <hip/hip_runtime.h>
#include <stdint.h>

typedef unsigned short u16;
typedef __attribute__((ext_vector_type(8))) short short8;
typedef __attribute__((ext_vector_type(4))) float f32x4;
typedef __attribute__((ext_vector_type(4))) unsigned short u16x4;

#define S_LEN 2048
#define NH 16
#define DMODEL 1024
#define NR 129
#define LOG2E 1.44269504f

#define MFMA(a,b,c) __builtin_amdgcn_mfma_f32_16x16x32_bf16((a),(b),(c),0,0,0)
// Compiler-only memory fence: LLVM's per-lane LDS alias model cannot see
// cross-lane write->read dependencies; this pins program order (HW executes
// same-wave DS ops in order, so no s_waitcnt is needed for memory ordering).
#define LDS_FENCE() __asm__ __volatile__("" ::: "memory")

__device__ __forceinline__ u16 f2bf(float f){            // RTNE
  uint32_t u = __float_as_uint(f);
  u += 0x7fff + ((u >> 16) & 1);
  return (u16)(u >> 16);
}
__device__ __forceinline__ u16 f2bfa(float f){           // RTNA (cheap, p>=0)
  return (u16)((__float_as_uint(f) + 0x8000u) >> 16);
}
__device__ __forceinline__ float bf2f(u16 h){ return __uint_as_float(((uint32_t)h) << 16); }

// ---------------- prep: convx + transw + convemb + mask*log2e, one launch ----------------
__global__ __launch_bounds__(256) void k_prep(const float* __restrict__ X,
                                              const float* __restrict__ Wq, const float* __restrict__ Wk,
                                              const float* __restrict__ Wv, const float* __restrict__ Wemb,
                                              const float* __restrict__ mask,
                                              u16* __restrict__ Xb, u16* __restrict__ Wt,
                                              u16* __restrict__ Eb, float* __restrict__ maskL){
  const int bid = blockIdx.x, tid = threadIdx.x;
  if (bid < 4096){
    int i = bid * 256 + tid;
    const float4* xp = (const float4*)X;
    float4 v = xp[i];
    u16x4 o; o.x = f2bf(v.x); o.y = f2bf(v.y); o.z = f2bf(v.z); o.w = f2bf(v.w);
    *(u16x4*)(Xb + (size_t)i * 4) = o;
  } else if (bid < 4864){
    int b2 = bid - 4096;
    int z = b2 >> 8;
    const float* W = (z == 0) ? Wq : (z == 1) ? Wk : Wv;
    u16* Ot = Wt + (size_t)z * 1024 * 1024;
    __shared__ float t[64][65];
    int k0 = ((b2 >> 4) & 15) * 64, n0 = (b2 & 15) * 64;
    int c = tid & 63, r0 = (tid >> 6) * 16;
    #pragma unroll
    for (int i = 0; i < 16; ++i) t[r0 + i][c] = W[(size_t)(k0 + r0 + i) * 1024 + n0 + c];
    __syncthreads();
    #pragma unroll
    for (int i = 0; i < 16; ++i) Ot[(size_t)(n0 + r0 + i) * 1024 + k0 + c] = f2bf(t[c][r0 + i]);
  } else if (bid < 4900){
    int idx = (bid - 4864) * 256 + tid;
    if (idx < 144 * 64){
      int r = idx >> 6;
      Eb[idx] = (r < NR) ? f2bf(Wemb[idx]) : (u16)0;
    }
  } else {
    int idx = (bid - 4900) * 256 + tid;
    maskL[idx] = mask[idx] * LOG2E;
  }
}

// ---------------- QKV GEMM ----------------
__global__ __launch_bounds__(256) void k_qkv(const u16* __restrict__ Xb, const u16* __restrict__ Wt,
                                             const float* __restrict__ bq, const float* __restrict__ bk,
                                             const float* __restrict__ bv,
                                             u16* __restrict__ Qs, u16* __restrict__ Kb, u16* __restrict__ Vb){
  const int z = blockIdx.z;
  const u16* W = Wt + (size_t)z * 1024 * 1024;
  const float* bias = (z == 0) ? bq : (z == 1) ? bk : bv;
  u16* outp = (z == 0) ? Qs : (z == 1) ? Kb : Vb;
  const float vs = (z == 0) ? 0.125f * LOG2E : 1.0f;
  const int n0 = blockIdx.x * 128, m0 = blockIdx.y * 128;
  const int tid = threadIdx.x, w = tid >> 6, lane = tid & 63, l15 = lane & 15, quad = lane >> 4;
  const int wm = (w >> 1) * 64, wn = (w & 1) * 64;
  __shared__ __attribute__((aligned(16))) u16 As[128][40];
  __shared__ __attribute__((aligned(16))) u16 Bs[128][40];
  f32x4 acc[4][4];
  #pragma unroll
  for (int i = 0; i < 4; ++i)
    #pragma unroll
    for (int j = 0; j < 4; ++j) acc[i][j] = (f32x4){0.f,0.f,0.f,0.f};

  for (int k0 = 0; k0 < 1024; k0 += 32){
    __syncthreads();
    #pragma unroll
    for (int i = 0; i < 2; ++i){
      int c = tid + i * 256; int r = c >> 2, ch = (c & 3) * 8;
      *(short8*)&As[r][ch] = *(const short8*)(Xb + (size_t)(m0 + r) * 1024 + k0 + ch);
      *(short8*)&Bs[r][ch] = *(const short8*)(W  + (size_t)(n0 + r) * 1024 + k0 + ch);
    }
    __syncthreads();
    short8 af[4], bfr[4];
    #pragma unroll
    for (int f = 0; f < 4; ++f){
      af[f]  = *(const short8*)&As[wm + f * 16 + l15][quad * 8];
      bfr[f] = *(const short8*)&Bs[wn + f * 16 + l15][quad * 8];
    }
    #pragma unroll
    for (int i = 0; i < 4; ++i)
      #pragma unroll
      for (int j = 0; j < 4; ++j) acc[i][j] = MFMA(af[i], bfr[j], acc[i][j]);
  }
  #pragma unroll
  for (int i = 0; i < 4; ++i){
    #pragma unroll
    for (int j = 0; j < 4; ++j){
      int col = n0 + wn + j * 16 + l15;
      float bsv = bias[col];
      int hh = col >> 6, jd = col & 63;
      #pragma unroll
      for (int r = 0; r < 4; ++r){
        int row = m0 + wm + i * 16 + quad * 4 + r;
        int bb = row >> 11, s = row & 2047;
        float vv = (acc[i][j][r] + bsv) * vs;
        outp[(((size_t)(bb * 16 + hh)) * S_LEN + s) * 64 + jd] = f2bf(vv);
      }
    }
  }
}

// ---------------- transpose V: [g][s][d] -> Vt[g][d][s] ----------------
__global__ __launch_bounds__(256) void k_transv(const u16* __restrict__ Vb, u16* __restrict__ Vt){
  const int g = blockIdx.y; const int s0 = blockIdx.x * 64;
  __shared__ __attribute__((aligned(16))) u16 t[64][72];
  const int tid = threadIdx.x;
  #pragma unroll
  for (int i = 0; i < 2; ++i){
    int c = tid + i * 256; int r = c >> 3, ch = (c & 7) * 8;
    *(short8*)&t[r][ch] = *(const short8*)(Vb + ((size_t)g * S_LEN + s0 + r) * 64 + ch);
  }
  __syncthreads();
  #pragma unroll
  for (int i = 0; i < 2; ++i){
    int c = tid + i * 256; int d = c >> 3, ch = (c & 7) * 8;
    short8 vv;
    #pragma unroll
    for (int u = 0; u < 8; ++u) vv[u] = (short)t[ch + u][d];
    *(short8*)(Vt + ((size_t)g * 64 + d) * S_LEN + s0 + ch) = vv;
  }
}

// ---------------- fused flash + rel_v band, TRANSPOSED (S^T = K·Q^T, O^T = V^T·P^T) ----------------
// Per lane: q = q0 + wm + l15 FIXED; 16 score elems/tile = 16 consecutive k (rows of S^T).
// No K/V LDS staging, no per-tile barriers. Cross-lane LDS round-trips are protected by
// (a) one __syncthreads() after init (QEb/Psb-zero) and (b) LDS_FENCE() between the Pt
// stores and Pt loads — without these, LLVM's per-lane alias model may hoist the reads
// above the writes (stale LDS -> Inf/NaN; rounds 5/6 failure).
__global__ __launch_bounds__(256) void k_flash(const u16* __restrict__ QS, const u16* __restrict__ KB,
                                               const u16* __restrict__ VT, const u16* __restrict__ EMBK,
                                               const float* __restrict__ maskL, const float* __restrict__ embv,
                                               float* __restrict__ out){
  const int g = blockIdx.y; const int b = g >> 4; const int h = g & 15;
  const int q0 = blockIdx.x * 64;
  const int tid = threadIdx.x;
  const int w = tid >> 6; const int lane = tid & 63;
  const int l15 = lane & 15; const int quad = lane >> 4;
  const int wm = w * 16;
  const int qg = q0 + wm + l15;                 // this lane's q (global)

  __shared__ union UQE {
    __attribute__((aligned(16))) u16 QEb[4][16][132];  // [wave][q-local=l15][ridx]
    __attribute__((aligned(16))) u16 EvT[64][136];     // [d][t] = emb_v[127-t][d]
  } uqe;                                               // 17,408 B
  __shared__ __attribute__((aligned(16))) u16 Psb[64][136];   // [q-local][t]  17,408 B
  __shared__ __attribute__((aligned(16))) u16 Pt[4][16][72];  // wave-private P (q x 64k) 9,216 B
  // total 44,032 B -> 3 blocks/CU

  // zero own Psb row chunks (wave-private rows wm..wm+15; quads cover 17 chunks)
  {
    short8 z8 = (short8){0,0,0,0,0,0,0,0};
    for (int c = quad; c < 17; c += 4) *(short8*)&Psb[wm + l15][c * 8] = z8;
  }

  // Q B-fragments (lane supplies column n=l15 -> q = q0+wm+l15)
  const u16* qptr = QS + ((size_t)g * S_LEN + qg) * 64 + quad * 8;
  short8 qa0 = *(const short8*)qptr;
  short8 qa1 = *(const short8*)(qptr + 32);

  // qe^T = emb_k · Q^T : C col = q-local = l15, row = ridx-local. Store QEb[w][l15][ridx].
  #pragma unroll
  for (int fn = 0; fn < 9; ++fn){
    const u16* ep = EMBK + (fn * 16 + l15) * 64 + quad * 8;
    short8 eb0 = *(const short8*)ep;
    short8 eb1 = *(const short8*)(ep + 32);
    f32x4 c = (f32x4){0.f,0.f,0.f,0.f};
    c = MFMA(eb0, qa0, c);
    c = MFMA(eb1, qa1, c);
    int rb = fn * 16 + quad * 4;
    #pragma unroll
    for (int r = 0; r < 4; ++r){
      int ridx = rb + r;
      if (ridx <= 128) uqe.QEb[w][l15][ridx] = f2bf(c[r]);
    }
  }
  __syncthreads();   // pin QEb writes (and Psb zero) before ANY read — do not remove

  float qeRs = bf2f(uqe.QEb[w][l15][0]);
  float qeLs = bf2f(uqe.QEb[w][l15][128]);

  f32x4 o[4];
  #pragma unroll
  for (int f = 0; f < 4; ++f) o[f] = (f32x4){0.f,0.f,0.f,0.f};
  float l_lane = 0.f, ll0 = 0.f, ll_mx = 0.f, rsb = 0.f;

  const u16* Kbase = KB + (size_t)g * S_LEN * 64 + l15 * 64 + quad * 8;
  const u16* Vbase = VT + (size_t)g * 64 * S_LEN + (size_t)l15 * S_LEN + quad * 8;
  const float* mbase = maskL + b * S_LEN + quad * 4;

  for (int kt = 0; kt < S_LEN; kt += 64){
    // K A-frags direct from global (rows = k)
    short8 kf0[4], kf1[4];
    #pragma unroll
    for (int fn = 0; fn < 4; ++fn){
      const u16* kp = Kbase + (size_t)(kt + fn * 16) * 64;
      kf0[fn] = *(const short8*)kp;
      kf1[fn] = *(const short8*)(kp + 32);
    }
    // V^T A-frags direct from global (rows = d)
    short8 vf0[4], vf1[4];
    #pragma unroll
    for (int fd = 0; fd < 4; ++fd){
      const u16* vp = Vbase + (size_t)fd * 16 * S_LEN + kt;
      vf0[fd] = *(const short8*)vp;
      vf1[fd] = *(const short8*)(vp + 32);
    }
    // scores S^T (rows k, cols q)
    f32x4 sc[4];
    #pragma unroll
    for (int fn = 0; fn < 4; ++fn){
      f32x4 c = (f32x4){0.f,0.f,0.f,0.f};
      c = MFMA(kf0[fn], qa0, c);
      c = MFMA(kf1[fn], qa1, c);
      sc[fn] = c;
    }

    if (kt <= q0 - 128){
      #pragma unroll
      for (int fn = 0; fn < 4; ++fn)
        #pragma unroll
        for (int r = 0; r < 4; ++r){
          float p = exp2f(sc[fn][r] + qeLs + mbase[kt + fn * 16 + r]);
          l_lane += p; sc[fn][r] = p;
        }
    } else if (kt >= q0 + 128){
      #pragma unroll
      for (int fn = 0; fn < 4; ++fn)
        #pragma unroll
        for (int r = 0; r < 4; ++r){
          float p = exp2f(sc[fn][r] + qeRs + mbase[kt + fn * 16 + r]);
          l_lane += p; sc[fn][r] = p;
        }
    } else {
      #pragma unroll
      for (int fn = 0; fn < 4; ++fn)
        #pragma unroll
        for (int r = 0; r < 4; ++r){
          int k = kt + fn * 16 + quad * 4 + r;
          int dq = qg - k + 64;
          int ridx = min(max(dq, 0), 128);
          float p = exp2f(sc[fn][r] + bf2f(uqe.QEb[w][l15][ridx]) + mbase[kt + fn * 16 + r]);
          l_lane += p;
          ll_mx += (dq >= 128) ? p : 0.f;
          if (dq >= 1 && dq <= 127){
            Psb[wm + l15][127 - dq] = f2bfa(p);
            rsb += p;
          }
          sc[fn][r] = p;
        }
    }

    // P -> Pt (wave-private): scalar u16 stores, row q=l15, col = k-local
    #pragma unroll
    for (int fn = 0; fn < 4; ++fn)
      #pragma unroll
      for (int r = 0; r < 4; ++r)
        Pt[w][l15][fn * 16 + quad * 4 + r] = f2bfa(sc[fn][r]);

    LDS_FENCE();   // cross-lane dep: Pt writes above feed Pt reads below — do not remove

    // PV: O^T += V^T . P^T   (B-frag = Pt row, b128)
    short8 pa0 = *(const short8*)&Pt[w][l15][quad * 8];
    short8 pa1 = *(const short8*)&Pt[w][l15][32 + quad * 8];
    #pragma unroll
    for (int fd = 0; fd < 4; ++fd){
      o[fd] = MFMA(vf0[fd], pa0, o[fd]);
      o[fd] = MFMA(vf1[fd], pa1, o[fd]);
    }

    if (kt == q0 - 128) ll0 = l_lane;   // all fully-left tiles processed
  }

  // ---- band epilogue ----
  __syncthreads();                       // all waves done with QEb -> reuse as EvT
  {
    int d = tid & 63;
    for (int tt = tid >> 6; tt < 128; tt += 4)
      uqe.EvT[d][tt] = f2bf(embv[(size_t)(127 - tt) * 64 + d]);
  }
  __syncthreads();

  f32x4 ob[4];
  #pragma unroll
  for (int f = 0; f < 4; ++f) ob[f] = (f32x4){0.f,0.f,0.f,0.f};
  #pragma unroll
  for (int ks = 0; ks < 4; ++ks){
    short8 pb = *(const short8*)&Psb[wm + l15][ks * 32 + quad * 8];
    #pragma unroll
    for (int fd = 0; fd < 4; ++fd){
      short8 ea = *(const short8*)&uqe.EvT[fd * 16 + l15][ks * 32 + quad * 8];
      ob[fd] = MFMA(ea, pb, ob[fd]);
    }
  }

  // reductions across the 4 lanes sharing q (xor 16, 32)
  float ll = ll0 + ll_mx;
  #pragma unroll
  for (int st = 16; st < 64; st <<= 1){
    l_lane += __shfl_xor(l_lane, st, 64);
    ll     += __shfl_xor(ll, st, 64);
    rsb    += __shfl_xor(rsb, st, 64);
  }
  float inv = 1.f / l_lane;
  float tl  = ll * inv;
  float trr = 1.f - tl - rsb * inv;

  float* obase = out + ((size_t)(b * S_LEN + qg)) * DMODEL + h * 64 + quad * 4;
  #pragma unroll
  for (int fd = 0; fd < 4; ++fd){
    float4 eL = *(const float4*)(embv + (size_t)128 * 64 + fd * 16 + quad * 4);
    float4 eR = *(const float4*)(embv + fd * 16 + quad * 4);
    float4 vv;
    vv.x = (o[fd][0] + ob[fd][0]) * inv + tl * eL.x + trr * eR.x;
    vv.y = (o[fd][1] + ob[fd][1]) * inv + tl * eL.y + trr * eR.y;
    vv.z = (o[fd][2] + ob[fd][2]) * inv + tl * eL.z + trr * eR.z;
    vv.w = (o[fd][3] + ob[fd][3]) * inv + tl * eL.w + trr * eR.w;
    *(float4*)(obase + fd * 16) = vv;
  }
}

extern "C" void kernel_launch(void* const* d_in, const int* in_sizes, int n_in,
                              void* d_out, int out_size, void* d_ws, size_t ws_size,
                              hipStream_t stream){
  const float* X    = (const float*)d_in[0];
  const float* mask = (const float*)d_in[1];
  const float* Wq   = (const float*)d_in[2];
  const float* bq   = (const float*)d_in[3];
  const float* Wk   = (const float*)d_in[4];
  const float* bk   = (const float*)d_in[5];
  const float* Wv   = (const float*)d_in[6];
  const float* bv   = (const float*)d_in[7];
  const float* embk = (const float*)d_in[8];
  const float* embv = (const float*)d_in[9];
  float* out = (float*)d_out;
  char* ws = (char*)d_ws;

  u16* XB   = (u16*)(ws + 0);            // 8,388,608
  u16* WT   = (u16*)(ws + 8388608);      // 6,291,456
  u16* EKB  = (u16*)(ws + 14680064);     // 18,432
  u16* QS   = (u16*)(ws + 14698496);     // 8,388,608
  u16* KB   = (u16*)(ws + 23087104);     // 8,388,608
  u16* VB   = (u16*)(ws + 31475712);     // 8,388,608
  u16* VT   = (u16*)(ws + 39864320);     // 8,388,608
  float* MSL = (float*)(ws + 48252928);  // 16,384

  k_prep   <<<4916, 256, 0, stream>>>(X, Wq, Wk, Wv, embk, mask, XB, WT, EKB, MSL);
  k_qkv    <<<dim3(8, 32, 3), 256, 0, stream>>>(XB, WT, bq, bk, bv, QS, KB, VB);
  k_transv <<<dim3(32, 32), 256, 0, stream>>>(VB, VT);
  k_flash  <<<dim3(32, 32), 256, 0, stream>>>(QS, KB, VT, EKB, MSL, embv, out);
}

// Round 8
// 408.099 us; speedup vs baseline: 1.0141x; 1.0141x over previous
//
#include <hip/hip_runtime.h>
#include <stdint.h>

typedef unsigned short u16;
typedef __attribute__((ext_vector_type(8))) short short8;
typedef __attribute__((ext_vector_type(4))) float f32x4;
typedef __attribute__((ext_vector_type(4))) unsigned short u16x4;

#define S_LEN 2048
#define NH 16
#define DMODEL 1024
#define NR 129
#define LOG2E 1.44269504f

#define MFMA(a,b,c) __builtin_amdgcn_mfma_f32_16x16x32_bf16((a),(b),(c),0,0,0)
// Compiler-only memory fence: LLVM's per-lane LDS alias model cannot see
// cross-lane write->read dependencies; this pins program order (HW executes
// same-wave DS ops in order). NOTE: it also blocks compiler load hoisting —
// all prefetches must be issued in program order BEFORE the fence.
#define LDS_FENCE() __asm__ __volatile__("" ::: "memory")

__device__ __forceinline__ u16 f2bf(float f){            // RTNE
  uint32_t u = __float_as_uint(f);
  u += 0x7fff + ((u >> 16) & 1);
  return (u16)(u >> 16);
}
__device__ __forceinline__ u16 f2bfa(float f){           // RTNA (cheap, p>=0)
  return (u16)((__float_as_uint(f) + 0x8000u) >> 16);
}
__device__ __forceinline__ float bf2f(u16 h){ return __uint_as_float(((uint32_t)h) << 16); }

// ---------------- prep: convx + transw + convemb + mask*log2e, one launch ----------------
__global__ __launch_bounds__(256) void k_prep(const float* __restrict__ X,
                                              const float* __restrict__ Wq, const float* __restrict__ Wk,
                                              const float* __restrict__ Wv, const float* __restrict__ Wemb,
                                              const float* __restrict__ mask,
                                              u16* __restrict__ Xb, u16* __restrict__ Wt,
                                              u16* __restrict__ Eb, float* __restrict__ maskL){
  const int bid = blockIdx.x, tid = threadIdx.x;
  if (bid < 4096){
    int i = bid * 256 + tid;
    const float4* xp = (const float4*)X;
    float4 v = xp[i];
    u16x4 o; o.x = f2bf(v.x); o.y = f2bf(v.y); o.z = f2bf(v.z); o.w = f2bf(v.w);
    *(u16x4*)(Xb + (size_t)i * 4) = o;
  } else if (bid < 4864){
    int b2 = bid - 4096;
    int z = b2 >> 8;
    const float* W = (z == 0) ? Wq : (z == 1) ? Wk : Wv;
    u16* Ot = Wt + (size_t)z * 1024 * 1024;
    __shared__ float t[64][65];
    int k0 = ((b2 >> 4) & 15) * 64, n0 = (b2 & 15) * 64;
    int c = tid & 63, r0 = (tid >> 6) * 16;
    #pragma unroll
    for (int i = 0; i < 16; ++i) t[r0 + i][c] = W[(size_t)(k0 + r0 + i) * 1024 + n0 + c];
    __syncthreads();
    #pragma unroll
    for (int i = 0; i < 16; ++i) Ot[(size_t)(n0 + r0 + i) * 1024 + k0 + c] = f2bf(t[c][r0 + i]);
  } else if (bid < 4900){
    int idx = (bid - 4864) * 256 + tid;
    if (idx < 144 * 64){
      int r = idx >> 6;
      Eb[idx] = (r < NR) ? f2bf(Wemb[idx]) : (u16)0;
    }
  } else {
    int idx = (bid - 4900) * 256 + tid;
    maskL[idx] = mask[idx] * LOG2E;
  }
}

// ---------------- QKV GEMM ----------------
__global__ __launch_bounds__(256) void k_qkv(const u16* __restrict__ Xb, const u16* __restrict__ Wt,
                                             const float* __restrict__ bq, const float* __restrict__ bk,
                                             const float* __restrict__ bv,
                                             u16* __restrict__ Qs, u16* __restrict__ Kb, u16* __restrict__ Vb){
  const int z = blockIdx.z;
  const u16* W = Wt + (size_t)z * 1024 * 1024;
  const float* bias = (z == 0) ? bq : (z == 1) ? bk : bv;
  u16* outp = (z == 0) ? Qs : (z == 1) ? Kb : Vb;
  const float vs = (z == 0) ? 0.125f * LOG2E : 1.0f;
  const int n0 = blockIdx.x * 128, m0 = blockIdx.y * 128;
  const int tid = threadIdx.x, w = tid >> 6, lane = tid & 63, l15 = lane & 15, quad = lane >> 4;
  const int wm = (w >> 1) * 64, wn = (w & 1) * 64;
  __shared__ __attribute__((aligned(16))) u16 As[128][40];
  __shared__ __attribute__((aligned(16))) u16 Bs[128][40];
  f32x4 acc[4][4];
  #pragma unroll
  for (int i = 0; i < 4; ++i)
    #pragma unroll
    for (int j = 0; j < 4; ++j) acc[i][j] = (f32x4){0.f,0.f,0.f,0.f};

  for (int k0 = 0; k0 < 1024; k0 += 32){
    __syncthreads();
    #pragma unroll
    for (int i = 0; i < 2; ++i){
      int c = tid + i * 256; int r = c >> 2, ch = (c & 3) * 8;
      *(short8*)&As[r][ch] = *(const short8*)(Xb + (size_t)(m0 + r) * 1024 + k0 + ch);
      *(short8*)&Bs[r][ch] = *(const short8*)(W  + (size_t)(n0 + r) * 1024 + k0 + ch);
    }
    __syncthreads();
    short8 af[4], bfr[4];
    #pragma unroll
    for (int f = 0; f < 4; ++f){
      af[f]  = *(const short8*)&As[wm + f * 16 + l15][quad * 8];
      bfr[f] = *(const short8*)&Bs[wn + f * 16 + l15][quad * 8];
    }
    #pragma unroll
    for (int i = 0; i < 4; ++i)
      #pragma unroll
      for (int j = 0; j < 4; ++j) acc[i][j] = MFMA(af[i], bfr[j], acc[i][j]);
  }
  #pragma unroll
  for (int i = 0; i < 4; ++i){
    #pragma unroll
    for (int j = 0; j < 4; ++j){
      int col = n0 + wn + j * 16 + l15;
      float bsv = bias[col];
      int hh = col >> 6, jd = col & 63;
      #pragma unroll
      for (int r = 0; r < 4; ++r){
        int row = m0 + wm + i * 16 + quad * 4 + r;
        int bb = row >> 11, s = row & 2047;
        float vv = (acc[i][j][r] + bsv) * vs;
        outp[(((size_t)(bb * 16 + hh)) * S_LEN + s) * 64 + jd] = f2bf(vv);
      }
    }
  }
}

// ---------------- transpose V: [g][s][d] -> Vt[g][d][s] ----------------
__global__ __launch_bounds__(256) void k_transv(const u16* __restrict__ Vb, u16* __restrict__ Vt){
  const int g = blockIdx.y; const int s0 = blockIdx.x * 64;
  __shared__ __attribute__((aligned(16))) u16 t[64][72];
  const int tid = threadIdx.x;
  #pragma unroll
  for (int i = 0; i < 2; ++i){
    int c = tid + i * 256; int r = c >> 3, ch = (c & 7) * 8;
    *(short8*)&t[r][ch] = *(const short8*)(Vb + ((size_t)g * S_LEN + s0 + r) * 64 + ch);
  }
  __syncthreads();
  #pragma unroll
  for (int i = 0; i < 2; ++i){
    int c = tid + i * 256; int d = c >> 3, ch = (c & 7) * 8;
    short8 vv;
    #pragma unroll
    for (int u = 0; u < 8; ++u) vv[u] = (short)t[ch + u][d];
    *(short8*)(Vt + ((size_t)g * 64 + d) * S_LEN + s0 + ch) = vv;
  }
}

// ---------------- fused flash + rel_v band, TRANSPOSED + K-prefetch double buffer ----------------
// S^T = K·Q^T, O^T = V^T·P^T; per lane q = q0+wm+l15 fixed. K fragments are register
// double-buffered one tile ahead (issued in program order BEFORE the LDS fence, which
// otherwise blocks all compiler load hoisting — round 7's 2x stall). V frags issued at
// body top, covered by QK-MFMA+softmax. Pt round-trip & QEb protected per round-7 rules.
__global__ __launch_bounds__(256) void k_flash(const u16* __restrict__ QS, const u16* __restrict__ KB,
                                               const u16* __restrict__ VT, const u16* __restrict__ EMBK,
                                               const float* __restrict__ maskL, const float* __restrict__ embv,
                                               float* __restrict__ out){
  const int g = blockIdx.y; const int b = g >> 4; const int h = g & 15;
  const int q0 = blockIdx.x * 64;
  const int tid = threadIdx.x;
  const int w = tid >> 6; const int lane = tid & 63;
  const int l15 = lane & 15; const int quad = lane >> 4;
  const int wm = w * 16;
  const int qg = q0 + wm + l15;                 // this lane's q (global)

  __shared__ union UQE {
    __attribute__((aligned(16))) u16 QEb[4][16][132];  // [wave][q-local=l15][ridx]
    __attribute__((aligned(16))) u16 EvT[64][136];     // [d][t] = emb_v[127-t][d]
  } uqe;                                               // 17,408 B
  __shared__ __attribute__((aligned(16))) u16 Psb[64][136];   // [q-local][t]  17,408 B
  __shared__ __attribute__((aligned(16))) u16 Pt[4][16][72];  // wave-private P (q x 64k) 9,216 B
  // total 44,032 B -> 3 blocks/CU

  // zero own Psb row chunks
  {
    short8 z8 = (short8){0,0,0,0,0,0,0,0};
    for (int c = quad; c < 17; c += 4) *(short8*)&Psb[wm + l15][c * 8] = z8;
  }

  // Q B-fragments
  const u16* qptr = QS + ((size_t)g * S_LEN + qg) * 64 + quad * 8;
  short8 qa0 = *(const short8*)qptr;
  short8 qa1 = *(const short8*)(qptr + 32);

  // qe^T = emb_k · Q^T -> QEb[w][l15][ridx]
  #pragma unroll
  for (int fn = 0; fn < 9; ++fn){
    const u16* ep = EMBK + (fn * 16 + l15) * 64 + quad * 8;
    short8 eb0 = *(const short8*)ep;
    short8 eb1 = *(const short8*)(ep + 32);
    f32x4 c = (f32x4){0.f,0.f,0.f,0.f};
    c = MFMA(eb0, qa0, c);
    c = MFMA(eb1, qa1, c);
    int rb = fn * 16 + quad * 4;
    #pragma unroll
    for (int r = 0; r < 4; ++r){
      int ridx = rb + r;
      if (ridx <= 128) uqe.QEb[w][l15][ridx] = f2bf(c[r]);
    }
  }
  __syncthreads();   // pin QEb writes (and Psb zero) before ANY read — do not remove

  const float qeRs = bf2f(uqe.QEb[w][l15][0]);
  const float qeLs = bf2f(uqe.QEb[w][l15][128]);

  f32x4 o[4];
  #pragma unroll
  for (int f = 0; f < 4; ++f) o[f] = (f32x4){0.f,0.f,0.f,0.f};
  float l_lane = 0.f, ll0 = 0.f, ll_mx = 0.f, rsb = 0.f;

  const u16* Kbase = KB + (size_t)g * S_LEN * 64 + l15 * 64 + quad * 8;
  const u16* Vbase = VT + (size_t)g * 64 * S_LEN + (size_t)l15 * S_LEN + quad * 8;
  const float* mbase = maskL + b * S_LEN + quad * 4;

  auto loadK = [&](int kt, short8 k0[4], short8 k1[4]){
    #pragma unroll
    for (int fn = 0; fn < 4; ++fn){
      const u16* kp = Kbase + (size_t)(kt + fn * 16) * 64;
      k0[fn] = *(const short8*)kp;
      k1[fn] = *(const short8*)(kp + 32);
    }
  };

  auto body = [&](int kt, const short8 k0[4], const short8 k1[4]){
    // V^T A-frags (issued first: covered by QK MFMA + softmax below)
    short8 vf0[4], vf1[4];
    #pragma unroll
    for (int fd = 0; fd < 4; ++fd){
      const u16* vp = Vbase + (size_t)fd * 16 * S_LEN + kt;
      vf0[fd] = *(const short8*)vp;
      vf1[fd] = *(const short8*)(vp + 32);
    }
    // mask (pre-scaled by log2e), vectorized
    float4 mv[4];
    #pragma unroll
    for (int fn = 0; fn < 4; ++fn) mv[fn] = *(const float4*)(mbase + kt + fn * 16);

    // scores S^T (rows k, cols q)
    f32x4 sc[4];
    #pragma unroll
    for (int fn = 0; fn < 4; ++fn){
      f32x4 c = (f32x4){0.f,0.f,0.f,0.f};
      c = MFMA(k0[fn], qa0, c);
      c = MFMA(k1[fn], qa1, c);
      sc[fn] = c;
    }

    if (kt <= q0 - 128){
      #pragma unroll
      for (int fn = 0; fn < 4; ++fn){
        const float* m4 = (const float*)&mv[fn];
        #pragma unroll
        for (int r = 0; r < 4; ++r){
          float p = exp2f(sc[fn][r] + qeLs + m4[r]);
          l_lane += p; sc[fn][r] = p;
        }
      }
    } else if (kt >= q0 + 128){
      #pragma unroll
      for (int fn = 0; fn < 4; ++fn){
        const float* m4 = (const float*)&mv[fn];
        #pragma unroll
        for (int r = 0; r < 4; ++r){
          float p = exp2f(sc[fn][r] + qeRs + m4[r]);
          l_lane += p; sc[fn][r] = p;
        }
      }
    } else {
      #pragma unroll
      for (int fn = 0; fn < 4; ++fn){
        const float* m4 = (const float*)&mv[fn];
        #pragma unroll
        for (int r = 0; r < 4; ++r){
          int k = kt + fn * 16 + quad * 4 + r;
          int dq = qg - k + 64;
          int ridx = min(max(dq, 0), 128);
          float p = exp2f(sc[fn][r] + bf2f(uqe.QEb[w][l15][ridx]) + m4[r]);
          l_lane += p;
          ll_mx += (dq >= 128) ? p : 0.f;
          if (dq >= 1 && dq <= 127){
            Psb[wm + l15][127 - dq] = f2bfa(p);
            rsb += p;
          }
          sc[fn][r] = p;
        }
      }
    }

    // P -> Pt (wave-private): scalar u16 stores
    #pragma unroll
    for (int fn = 0; fn < 4; ++fn)
      #pragma unroll
      for (int r = 0; r < 4; ++r)
        Pt[w][l15][fn * 16 + quad * 4 + r] = f2bfa(sc[fn][r]);

    LDS_FENCE();   // cross-lane dep: Pt writes feed Pt reads — do not remove

    // PV: O^T += V^T . P^T
    short8 pa0 = *(const short8*)&Pt[w][l15][quad * 8];
    short8 pa1 = *(const short8*)&Pt[w][l15][32 + quad * 8];
    #pragma unroll
    for (int fd = 0; fd < 4; ++fd){
      o[fd] = MFMA(vf0[fd], pa0, o[fd]);
      o[fd] = MFMA(vf1[fd], pa1, o[fd]);
    }

    if (kt == q0 - 128) ll0 = l_lane;   // all fully-left tiles processed
  };

  // K register double buffer, unroll-by-2
  short8 kA0[4], kA1[4], kB0[4], kB1[4];
  loadK(0, kA0, kA1);
  for (int kt = 0; kt < S_LEN; kt += 128){
    loadK(kt + 64, kB0, kB1);
    body(kt, kA0, kA1);
    if (kt + 128 < S_LEN) loadK(kt + 128, kA0, kA1);
    body(kt + 64, kB0, kB1);
  }

  // ---- band epilogue ----
  __syncthreads();                       // all waves done with QEb -> reuse as EvT
  {
    int d = tid & 63;
    for (int tt = tid >> 6; tt < 128; tt += 4)
      uqe.EvT[d][tt] = f2bf(embv[(size_t)(127 - tt) * 64 + d]);
  }
  __syncthreads();

  f32x4 ob[4];
  #pragma unroll
  for (int f = 0; f < 4; ++f) ob[f] = (f32x4){0.f,0.f,0.f,0.f};
  #pragma unroll
  for (int ks = 0; ks < 4; ++ks){
    short8 pb = *(const short8*)&Psb[wm + l15][ks * 32 + quad * 8];
    #pragma unroll
    for (int fd = 0; fd < 4; ++fd){
      short8 ea = *(const short8*)&uqe.EvT[fd * 16 + l15][ks * 32 + quad * 8];
      ob[fd] = MFMA(ea, pb, ob[fd]);
    }
  }

  // reductions across the 4 lanes sharing q (xor 16, 32)
  float ll = ll0 + ll_mx;
  #pragma unroll
  for (int st = 16; st < 64; st <<= 1){
    l_lane += __shfl_xor(l_lane, st, 64);
    ll     += __shfl_xor(ll, st, 64);
    rsb    += __shfl_xor(rsb, st, 64);
  }
  float inv = 1.f / l_lane;
  float tl  = ll * inv;
  float trr = 1.f - tl - rsb * inv;

  float* obase = out + ((size_t)(b * S_LEN + qg)) * DMODEL + h * 64 + quad * 4;
  #pragma unroll
  for (int fd = 0; fd < 4; ++fd){
    float4 eL = *(const float4*)(embv + (size_t)128 * 64 + fd * 16 + quad * 4);
    float4 eR = *(const float4*)(embv + fd * 16 + quad * 4);
    float4 vv;
    vv.x = (o[fd][0] + ob[fd][0]) * inv + tl * eL.x + trr * eR.x;
    vv.y = (o[fd][1] + ob[fd][1]) * inv + tl * eL.y + trr * eR.y;
    vv.z = (o[fd][2] + ob[fd][2]) * inv + tl * eL.z + trr * eR.z;
    vv.w = (o[fd][3] + ob[fd][3]) * inv + tl * eL.w + trr * eR.w;
    *(float4*)(obase + fd * 16) = vv;
  }
}

extern "C" void kernel_launch(void* const* d_in, const int* in_sizes, int n_in,
                              void* d_out, int out_size, void* d_ws, size_t ws_size,
                              hipStream_t stream){
  const float* X    = (const float*)d_in[0];
  const float* mask = (const float*)d_in[1];
  const float* Wq   = (const float*)d_in[2];
  const float* bq   = (const float*)d_in[3];
  const float* Wk   = (const float*)d_in[4];
  const float* bk   = (const float*)d_in[5];
  const float* Wv   = (const float*)d_in[6];
  const float* bv   = (const float*)d_in[7];
  const float* embk = (const float*)d_in[8];
  const float* embv = (const float*)d_in[9];
  float* out = (float*)d_out;
  char* ws = (char*)d_ws;

  u16* XB   = (u16*)(ws + 0);            // 8,388,608
  u16* WT   = (u16*)(ws + 8388608);      // 6,291,456
  u16* EKB  = (u16*)(ws + 14680064);     // 18,432
  u16* QS   = (u16*)(ws + 14698496);     // 8,388,608
  u16* KB   = (u16*)(ws + 23087104);     // 8,388,608
  u16* VB   = (u16*)(ws + 31475712);     // 8,388,608
  u16* VT   = (u16*)(ws + 39864320);     // 8,388,608
  float* MSL = (float*)(ws + 48252928);  // 16,384

  k_prep   <<<4916, 256, 0, stream>>>(X, Wq, Wk, Wv, embk, mask, XB, WT, EKB, MSL);
  k_qkv    <<<dim3(8, 32, 3), 256, 0, stream>>>(XB, WT, bq, bk, bv, QS, KB, VB);
  k_transv <<<dim3(32, 32), 256, 0, stream>>>(VB, VT);
  k_flash  <<<dim3(32, 32), 256, 0, stream>>>(QS, KB, VT, EKB, MSL, embv, out);
}